// Round 1
// baseline (465.695 us; speedup 1.0000x reference)
//
#include <hip/hip_runtime.h>
#include <math.h>

#define Vn 5
#define Cn 32
#define Hn 384
#define Wn 384
#define Dn 4
#define Gn 8
#define HWn (Hn*Wn)   // 147456

// ---------- small 3x3 helpers (device) ----------
__device__ __forceinline__ void inv3(const float* m, float* o){
    float a=m[0],b=m[1],c=m[2],d=m[3],e=m[4],f=m[5],g=m[6],h=m[7],i=m[8];
    float A =  e*i - f*h;
    float B = -(d*i - f*g);
    float C =  d*h - e*g;
    float det = a*A + b*B + c*C;
    float r = 1.f/det;
    o[0] = A*r;            o[1] = -(b*i - c*h)*r;  o[2] =  (b*f - c*e)*r;
    o[3] = B*r;            o[4] =  (a*i - c*g)*r;  o[5] = -(a*f - c*d)*r;
    o[6] = C*r;            o[7] = -(a*h - b*g)*r;  o[8] =  (a*e - b*d)*r;
}
__device__ __forceinline__ void mm3(const float* a, const float* b, float* o){
    #pragma unroll
    for (int r=0;r<3;r++)
        #pragma unroll
        for (int c=0;c<3;c++)
            o[r*3+c] = a[r*3+0]*b[0*3+c] + a[r*3+1]*b[1*3+c] + a[r*3+2]*b[2*3+c];
}
__device__ __forceinline__ void mv3(const float* a, const float* v, float* o){
    #pragma unroll
    for (int r=0;r<3;r++)
        o[r] = a[r*3+0]*v[0] + a[r*3+1]*v[1] + a[r*3+2]*v[2];
}

// ---------- transpose source views (C,H,W) -> (H*W, C) ----------
__global__ __launch_bounds__(256)
void transpose_kernel(const float* __restrict__ feat, float* __restrict__ featT){
    __shared__ float tile[32][33];
    const int s    = blockIdx.y;          // 0..3 -> view s+1
    const int p0   = blockIdx.x * 32;     // pixel tile base
    const int lane = threadIdx.x & 31;
    const int row8 = threadIdx.x >> 5;    // 0..7
    const float* src = feat + (size_t)(s+1)*Cn*HWn;
    #pragma unroll
    for (int r=0;r<4;r++){
        int ch = r*8 + row8;
        tile[ch][lane] = src[(size_t)ch*HWn + p0 + lane];
    }
    __syncthreads();
    float* dst = featT + (size_t)s*HWn*Cn;
    #pragma unroll
    for (int r=0;r<4;r++){
        int p = r*8 + row8;
        dst[(size_t)(p0+p)*Cn + lane] = tile[lane][p];
    }
}

// ---------- bilinear tap ----------
template<bool TRANS>
__device__ __forceinline__ void sample_tap(const float* __restrict__ feat,
                                           const float* __restrict__ featT,
                                           int s, float xi, float yi, float w,
                                           const float* ref, float* sg)
{
    const bool valid = (xi >= 0.f) && (xi <= (float)(Wn-1)) &&
                       (yi >= 0.f) && (yi <= (float)(Hn-1));
    const float wt = valid ? w : 0.f;
    if (wt != 0.f){
        const int xc = (int)xi;
        const int yc = (int)yi;
        if (TRANS){
            const float4* p = (const float4*)(featT + ((size_t)s*HWn + (size_t)yc*Wn + xc)*Cn);
            #pragma unroll
            for (int g=0; g<Gn; g++){
                const float4 f = p[g];
                float dt = f.x*ref[4*g];
                dt = fmaf(f.y, ref[4*g+1], dt);
                dt = fmaf(f.z, ref[4*g+2], dt);
                dt = fmaf(f.w, ref[4*g+3], dt);
                sg[g] = fmaf(wt, dt, sg[g]);
            }
        } else {
            const float* p = feat + (size_t)(s+1)*Cn*HWn + (size_t)yc*Wn + xc;
            #pragma unroll
            for (int g=0; g<Gn; g++){
                float dt = 0.f;
                #pragma unroll
                for (int j=0;j<4;j++)
                    dt = fmaf(p[(size_t)(4*g+j)*HWn], ref[4*g+j], dt);
                sg[g] = fmaf(wt, dt, sg[g]);
            }
        }
    }
}

// ---------- fused main kernel ----------
template<bool TRANS>
__global__ __launch_bounds__(256)
void gbinet_kernel(const float* __restrict__ feat,
                   const float* __restrict__ depths,
                   const float* __restrict__ Kin,
                   const float* __restrict__ Ein,
                   const float* __restrict__ w0, const float* __restrict__ b0,
                   const float* __restrict__ w1, const float* __restrict__ b1,
                   const float* __restrict__ w2, const float* __restrict__ b2,
                   const float* __restrict__ featT,
                   float* __restrict__ out)
{
    __shared__ float sW0[128], sW1[128], sB0[16], sB1[8], sW2[8], sB2s[1];
    __shared__ float sM[48];   // per source view: A[9] + c[3]
    const int t = threadIdx.x;
    if (t < 128){ sW0[t] = w0[t]; sW1[t] = w1[t]; }
    if (t < 16) sB0[t] = b0[t];
    if (t < 8){ sB1[t] = b1[t]; sW2[t] = w2[t]; }
    if (t == 0){
        sB2s[0] = b2[0];
        // fold projection chain: uvd = A_s * (x,y,1) * depth + c_s
        float K0inv[9]; inv3(Kin, K0inv);
        float R0[9], t0[3];
        #pragma unroll
        for (int r=0;r<3;r++){
            #pragma unroll
            for (int c=0;c<3;c++) R0[r*3+c] = Ein[r*4+c];
            t0[r] = Ein[r*4+3];
        }
        float R0inv[9]; inv3(R0, R0inv);
        float M0[9]; mm3(R0inv, K0inv, M0);
        float Rt0[3]; mv3(R0inv, t0, Rt0);
        for (int s=1;s<Vn;s++){
            const float* Ks = Kin + s*9;
            const float* Es = Ein + s*12;
            float Rs[9], ts[3];
            #pragma unroll
            for (int r=0;r<3;r++){
                #pragma unroll
                for (int c=0;c<3;c++) Rs[r*3+c] = Es[r*4+c];
                ts[r] = Es[r*4+3];
            }
            float T1[9]; mm3(Rs, M0, T1);
            float A[9];  mm3(Ks, T1, A);
            float Rr[3]; mv3(Rs, Rt0, Rr);
            float tv[3] = { ts[0]-Rr[0], ts[1]-Rr[1], ts[2]-Rr[2] };
            float cv[3]; mv3(Ks, tv, cv);
            float* dm = &sM[(s-1)*12];
            #pragma unroll
            for (int i=0;i<9;i++) dm[i] = A[i];
            #pragma unroll
            for (int i=0;i<3;i++) dm[9+i] = cv[i];
        }
    }
    __syncthreads();

    const int pix = blockIdx.x*256 + t;
    const float xg = (float)(pix % Wn) + 0.5f;
    const float yg = (float)(pix / Wn) + 0.5f;

    float ref[Cn];
    #pragma unroll
    for (int c=0;c<Cn;c++) ref[c] = feat[(size_t)c*HWn + pix];   // view 0, b 0
    float dep[Dn];
    #pragma unroll
    for (int d=0;d<Dn;d++) dep[d] = depths[(size_t)d*HWn + pix];

    float acc[Gn][Dn];
    #pragma unroll
    for (int g=0;g<Gn;g++)
        #pragma unroll
        for (int d=0;d<Dn;d++) acc[g][d] = 0.f;
    float wsum = 0.f;

    for (int s=0;s<Vn-1;s++){
        const float* M = &sM[s*12];
        const float bx = M[0]*xg + M[1]*yg + M[2];
        const float by = M[3]*xg + M[4]*yg + M[5];
        const float bz = M[6]*xg + M[7]*yg + M[8];
        float sim[Gn][Dn];
        #pragma unroll
        for (int d=0;d<Dn;d++){
            const float dd = dep[d];
            const float ux = fmaf(bx, dd, M[9]);
            const float uy = fmaf(by, dd, M[10]);
            const float uz = fmaf(bz, dd, M[11]) + 1e-9f;
            const float rz = 1.f/uz;
            const float px = ux*rz, py = uy*rz;
            const float x0 = floorf(px), y0 = floorf(py);
            const float wx1 = px - x0, wy1 = py - y0;
            const float wx0 = 1.f - wx1, wy0 = 1.f - wy1;
            float sg[Gn];
            #pragma unroll
            for (int g=0; g<Gn; g++) sg[g] = 0.f;
            sample_tap<TRANS>(feat, featT, s, x0,     y0,     wx0*wy0, ref, sg);
            sample_tap<TRANS>(feat, featT, s, x0+1.f, y0,     wx1*wy0, ref, sg);
            sample_tap<TRANS>(feat, featT, s, x0,     y0+1.f, wx0*wy1, ref, sg);
            sample_tap<TRANS>(feat, featT, s, x0+1.f, y0+1.f, wx1*wy1, ref, sg);
            #pragma unroll
            for (int g=0; g<Gn; g++) sim[g][d] = sg[g]*0.25f;   // mean over 4 ch/group
        }
        // pixelwise net over 4 depths; max(sigmoid) == sigmoid(max logit)
        float maxlog = -3.0e38f;
        #pragma unroll
        for (int d=0; d<Dn; d++){
            float h[16];
            #pragma unroll
            for (int o=0;o<16;o++){
                float a = sB0[o];
                #pragma unroll
                for (int g=0; g<Gn; g++) a = fmaf(sW0[o*Gn+g], sim[g][d], a);
                h[o] = fmaxf(a, 0.f);
            }
            float lg = sB2s[0];
            #pragma unroll
            for (int o=0;o<8;o++){
                float a = sB1[o];
                #pragma unroll
                for (int i=0;i<16;i++) a = fmaf(sW1[o*16+i], h[i], a);
                lg = fmaf(sW2[o], fmaxf(a, 0.f), lg);
            }
            maxlog = fmaxf(maxlog, lg);
        }
        const float vw = 1.f/(1.f + __expf(-maxlog));
        wsum += vw;
        #pragma unroll
        for (int g=0;g<Gn;g++)
            #pragma unroll
            for (int d=0;d<Dn;d++) acc[g][d] = fmaf(sim[g][d], vw, acc[g][d]);
    }

    const float invw = 1.f/wsum;
    #pragma unroll
    for (int g=0;g<Gn;g++)
        #pragma unroll
        for (int d=0;d<Dn;d++)
            out[((size_t)(g*Dn+d))*HWn + pix] = acc[g][d]*invw;
}

extern "C" void kernel_launch(void* const* d_in, const int* in_sizes, int n_in,
                              void* d_out, int out_size, void* d_ws, size_t ws_size,
                              hipStream_t stream)
{
    (void)in_sizes; (void)n_in; (void)out_size;
    const float* feat   = (const float*)d_in[0];
    const float* depths = (const float*)d_in[1];
    const float* K      = (const float*)d_in[2];
    const float* E      = (const float*)d_in[3];
    const float* w0     = (const float*)d_in[4];
    const float* b0     = (const float*)d_in[5];
    const float* w1     = (const float*)d_in[6];
    const float* b1     = (const float*)d_in[7];
    const float* w2     = (const float*)d_in[8];
    const float* b2     = (const float*)d_in[9];
    float* out   = (float*)d_out;
    float* featT = (float*)d_ws;

    const size_t needT = (size_t)(Vn-1)*HWn*Cn*sizeof(float);
    if (ws_size >= needT){
        dim3 g(HWn/32, Vn-1);
        transpose_kernel<<<g, 256, 0, stream>>>(feat, featT);
        gbinet_kernel<true><<<HWn/256, 256, 0, stream>>>(feat, depths, K, E,
                                                         w0,b0,w1,b1,w2,b2, featT, out);
    } else {
        gbinet_kernel<false><<<HWn/256, 256, 0, stream>>>(feat, depths, K, E,
                                                          w0,b0,w1,b1,w2,b2, featT, out);
    }
}

// Round 2
// 328.231 us; speedup vs baseline: 1.4188x; 1.4188x over previous
//
#include <hip/hip_runtime.h>
#include <math.h>

#define Vn 5
#define Cn 32
#define Hn 384
#define Wn 384
#define Dn 4
#define Gn 8
#define HWn (Hn*Wn)   // 147456

// ---------- small 3x3 helpers (device) ----------
__device__ __forceinline__ void inv3(const float* m, float* o){
    float a=m[0],b=m[1],c=m[2],d=m[3],e=m[4],f=m[5],g=m[6],h=m[7],i=m[8];
    float A =  e*i - f*h;
    float B = -(d*i - f*g);
    float C =  d*h - e*g;
    float det = a*A + b*B + c*C;
    float r = 1.f/det;
    o[0] = A*r;            o[1] = -(b*i - c*h)*r;  o[2] =  (b*f - c*e)*r;
    o[3] = B*r;            o[4] =  (a*i - c*g)*r;  o[5] = -(a*f - c*d)*r;
    o[6] = C*r;            o[7] = -(a*h - b*g)*r;  o[8] =  (a*e - b*d)*r;
}
__device__ __forceinline__ void mm3(const float* a, const float* b, float* o){
    #pragma unroll
    for (int r=0;r<3;r++)
        #pragma unroll
        for (int c=0;c<3;c++)
            o[r*3+c] = a[r*3+0]*b[0*3+c] + a[r*3+1]*b[1*3+c] + a[r*3+2]*b[2*3+c];
}
__device__ __forceinline__ void mv3(const float* a, const float* v, float* o){
    #pragma unroll
    for (int r=0;r<3;r++)
        o[r] = a[r*3+0]*v[0] + a[r*3+1]*v[1] + a[r*3+2]*v[2];
}

// ---------- transpose source views (C,H,W) -> (H*W, C), 256-px tiles ----------
__global__ __launch_bounds__(256)
void transpose_kernel(const float* __restrict__ feat, float* __restrict__ featT){
    __shared__ float tile[32*257];
    const int s  = blockIdx.y;            // 0..3 -> view s+1
    const int p0 = blockIdx.x * 256;      // pixel tile base
    const int t  = threadIdx.x;
    const float* src = feat + (size_t)(s+1)*Cn*HWn + p0;
    #pragma unroll
    for (int k=0;k<8;k++){
        const int i   = k*256 + t;
        const int px4 = (i & 63) * 4;
        const int ch  = i >> 6;
        const float4 v = *(const float4*)(src + (size_t)ch*HWn + px4);
        float* d = &tile[ch*257 + px4];
        d[0]=v.x; d[1]=v.y; d[2]=v.z; d[3]=v.w;
    }
    __syncthreads();
    float* dst = featT + (size_t)s*HWn*Cn + (size_t)p0*Cn;
    #pragma unroll
    for (int k=0;k<8;k++){
        const int i   = k*256 + t;
        const int ch4 = (i & 7) * 4;
        const int px  = i >> 3;
        float4 v;
        v.x = tile[(ch4+0)*257 + px];
        v.y = tile[(ch4+1)*257 + px];
        v.z = tile[(ch4+2)*257 + px];
        v.w = tile[(ch4+3)*257 + px];
        *(float4*)(dst + (size_t)px*Cn + ch4) = v;
    }
}

// ---------- bilinear tap (view base pre-resolved) ----------
template<bool TRANS>
__device__ __forceinline__ void sample_tap(const float* __restrict__ vbase,
                                           float xi, float yi, float w,
                                           const float* ref, float* sg)
{
    const bool valid = (xi >= 0.f) && (xi <= (float)(Wn-1)) &&
                       (yi >= 0.f) && (yi <= (float)(Hn-1));
    const float wt = valid ? w : 0.f;
    if (wt != 0.f){
        const int xc = (int)xi;
        const int yc = (int)yi;
        if (TRANS){
            const float4* p = (const float4*)(vbase + ((size_t)yc*Wn + xc)*Cn);
            #pragma unroll
            for (int g=0; g<Gn; g++){
                const float4 f = p[g];
                float dt = f.x*ref[4*g];
                dt = fmaf(f.y, ref[4*g+1], dt);
                dt = fmaf(f.z, ref[4*g+2], dt);
                dt = fmaf(f.w, ref[4*g+3], dt);
                sg[g] = fmaf(wt, dt, sg[g]);
            }
        } else {
            const float* p = vbase + (size_t)yc*Wn + xc;
            #pragma unroll
            for (int g=0; g<Gn; g++){
                float dt = 0.f;
                #pragma unroll
                for (int j=0;j<4;j++)
                    dt = fmaf(p[(size_t)(4*g+j)*HWn], ref[4*g+j], dt);
                sg[g] = fmaf(wt, dt, sg[g]);
            }
        }
    }
}

// ---------- fused main kernel: one thread per (pixel, source view) ----------
// Block = 256 threads = 64 pixels x 4 views. Lanes (t&~3)+{0..3} hold the 4
// views of one pixel and live in the same wave -> shfl_xor reduction.
template<bool TRANS>
__global__ __launch_bounds__(256, 4)   // cap 128 VGPR -> 4 waves/SIMD
void gbinet_kernel(const float* __restrict__ feat,
                   const float* __restrict__ depths,
                   const float* __restrict__ Kin,
                   const float* __restrict__ Ein,
                   const float* __restrict__ w0, const float* __restrict__ b0,
                   const float* __restrict__ w1, const float* __restrict__ b1,
                   const float* __restrict__ w2, const float* __restrict__ b2,
                   const float* __restrict__ featT,
                   float* __restrict__ out)
{
    __shared__ float sW0[128], sW1[128], sB0[16], sB1[8], sW2[8], sB2s[1];
    __shared__ float sM[48];            // per source view: A[9] + c[3]
    __shared__ float sOut[64*33];       // 64 pixels x 32 outputs (pad 33)
    const int t = threadIdx.x;
    if (t < 128){ sW0[t] = w0[t]; sW1[t] = w1[t]; }
    if (t < 16) sB0[t] = b0[t];
    if (t < 8){ sB1[t] = b1[t]; sW2[t] = w2[t]; }
    if (t == 0){
        sB2s[0] = b2[0];
        // fold projection chain: uvd = A_s * (x,y,1) * depth + c_s
        float K0inv[9]; inv3(Kin, K0inv);
        float R0[9], t0[3];
        #pragma unroll
        for (int r=0;r<3;r++){
            #pragma unroll
            for (int c=0;c<3;c++) R0[r*3+c] = Ein[r*4+c];
            t0[r] = Ein[r*4+3];
        }
        float R0inv[9]; inv3(R0, R0inv);
        float M0[9]; mm3(R0inv, K0inv, M0);
        float Rt0[3]; mv3(R0inv, t0, Rt0);
        for (int s=1;s<Vn;s++){
            const float* Ks = Kin + s*9;
            const float* Es = Ein + s*12;
            float Rs[9], ts[3];
            #pragma unroll
            for (int r=0;r<3;r++){
                #pragma unroll
                for (int c=0;c<3;c++) Rs[r*3+c] = Es[r*4+c];
                ts[r] = Es[r*4+3];
            }
            float T1[9]; mm3(Rs, M0, T1);
            float A[9];  mm3(Ks, T1, A);
            float Rr[3]; mv3(Rs, Rt0, Rr);
            float tv[3] = { ts[0]-Rr[0], ts[1]-Rr[1], ts[2]-Rr[2] };
            float cv[3]; mv3(Ks, tv, cv);
            float* dm = &sM[(s-1)*12];
            #pragma unroll
            for (int i=0;i<9;i++) dm[i] = A[i];
            #pragma unroll
            for (int i=0;i<3;i++) dm[9+i] = cv[i];
        }
    }
    __syncthreads();

    const int pixLocal = t >> 2;        // 0..63
    const int s        = t & 3;         // source view index (0..3 -> view s+1)
    const int pix      = blockIdx.x*64 + pixLocal;
    const float xg = (float)(pix % Wn) + 0.5f;
    const float yg = (float)(pix / Wn) + 0.5f;

    float ref[Cn];
    #pragma unroll
    for (int c=0;c<Cn;c++) ref[c] = feat[(size_t)c*HWn + pix];   // view 0
    float dep[Dn];
    #pragma unroll
    for (int d=0;d<Dn;d++) dep[d] = depths[(size_t)d*HWn + pix];

    const float* M = &sM[s*12];
    const float bx = M[0]*xg + M[1]*yg + M[2];
    const float by = M[3]*xg + M[4]*yg + M[5];
    const float bz = M[6]*xg + M[7]*yg + M[8];
    const float* vbase = TRANS ? (featT + (size_t)s*HWn*Cn)
                               : (feat + (size_t)(s+1)*Cn*HWn);

    float sim[Gn][Dn];
    #pragma unroll
    for (int d=0;d<Dn;d++){
        const float dd = dep[d];
        const float ux = fmaf(bx, dd, M[9]);
        const float uy = fmaf(by, dd, M[10]);
        const float uz = fmaf(bz, dd, M[11]) + 1e-9f;
        const float rz = 1.f/uz;
        const float px = ux*rz, py = uy*rz;
        const float x0 = floorf(px), y0 = floorf(py);
        const float wx1 = px - x0, wy1 = py - y0;
        const float wx0 = 1.f - wx1, wy0 = 1.f - wy1;
        float sg[Gn];
        #pragma unroll
        for (int g=0; g<Gn; g++) sg[g] = 0.f;
        sample_tap<TRANS>(vbase, x0,     y0,     wx0*wy0, ref, sg);
        sample_tap<TRANS>(vbase, x0+1.f, y0,     wx1*wy0, ref, sg);
        sample_tap<TRANS>(vbase, x0,     y0+1.f, wx0*wy1, ref, sg);
        sample_tap<TRANS>(vbase, x0+1.f, y0+1.f, wx1*wy1, ref, sg);
        #pragma unroll
        for (int g=0; g<Gn; g++) sim[g][d] = sg[g]*0.25f;  // mean over 4 ch/group
    }

    // pixelwise net over 4 depths; max(sigmoid) == sigmoid(max logit)
    float maxlog = -3.0e38f;
    #pragma unroll
    for (int d=0; d<Dn; d++){
        float h[16];
        #pragma unroll
        for (int o=0;o<16;o++){
            float a = sB0[o];
            #pragma unroll
            for (int g=0; g<Gn; g++) a = fmaf(sW0[o*Gn+g], sim[g][d], a);
            h[o] = fmaxf(a, 0.f);
        }
        float lg = sB2s[0];
        #pragma unroll
        for (int o=0;o<8;o++){
            float a = sB1[o];
            #pragma unroll
            for (int i=0;i<16;i++) a = fmaf(sW1[o*16+i], h[i], a);
            lg = fmaf(sW2[o], fmaxf(a, 0.f), lg);
        }
        maxlog = fmaxf(maxlog, lg);
    }
    const float vw = 1.f/(1.f + __expf(-maxlog));

    // scale by vw, butterfly-reduce across the 4 view lanes
    float wsum = vw;
    wsum += __shfl_xor(wsum, 1);
    wsum += __shfl_xor(wsum, 2);
    #pragma unroll
    for (int g=0;g<Gn;g++)
        #pragma unroll
        for (int d=0;d<Dn;d++){
            float v = sim[g][d]*vw;
            v += __shfl_xor(v, 1);
            v += __shfl_xor(v, 2);
            sim[g][d] = v;
        }

    if (s == 0){
        const float invw = 1.f/wsum;
        #pragma unroll
        for (int g=0;g<Gn;g++)
            #pragma unroll
            for (int d=0;d<Dn;d++)
                sOut[pixLocal*33 + g*Dn + d] = sim[g][d]*invw;
    }
    __syncthreads();

    // coalesced write-out: 32 planes x 64 pixels
    float* oBase = out + (size_t)blockIdx.x*64;
    #pragma unroll
    for (int k=0;k<8;k++){
        const int e     = k*256 + t;
        const int plane = e >> 6;
        const int pixel = e & 63;
        oBase[(size_t)plane*HWn + pixel] = sOut[pixel*33 + plane];
    }
}

extern "C" void kernel_launch(void* const* d_in, const int* in_sizes, int n_in,
                              void* d_out, int out_size, void* d_ws, size_t ws_size,
                              hipStream_t stream)
{
    (void)in_sizes; (void)n_in; (void)out_size;
    const float* feat   = (const float*)d_in[0];
    const float* depths = (const float*)d_in[1];
    const float* K      = (const float*)d_in[2];
    const float* E      = (const float*)d_in[3];
    const float* w0     = (const float*)d_in[4];
    const float* b0     = (const float*)d_in[5];
    const float* w1     = (const float*)d_in[6];
    const float* b1     = (const float*)d_in[7];
    const float* w2     = (const float*)d_in[8];
    const float* b2     = (const float*)d_in[9];
    float* out   = (float*)d_out;
    float* featT = (float*)d_ws;

    const size_t needT = (size_t)(Vn-1)*HWn*Cn*sizeof(float);
    if (ws_size >= needT){
        dim3 g(HWn/256, Vn-1);
        transpose_kernel<<<g, 256, 0, stream>>>(feat, featT);
        gbinet_kernel<true><<<HWn/64, 256, 0, stream>>>(feat, depths, K, E,
                                                        w0,b0,w1,b1,w2,b2, featT, out);
    } else {
        gbinet_kernel<false><<<HWn/64, 256, 0, stream>>>(feat, depths, K, E,
                                                         w0,b0,w1,b1,w2,b2, featT, out);
    }
}